// Round 11
// baseline (748.040 us; speedup 1.0000x reference)
//
#include <hip/hip_runtime.h>

#define NN 200000
#define NE 3200000
#define NG 400
#define NB 196        // ceil(NN / 1024) for node scan
#define BSHIFT 8      // 256 nodes per bucket
#define NBKT 782      // ceil(NN / 256)
#define EPB 3125      // edges per partition block (1024 blocks; was 12500/256 -> 9% occupancy)
#define SRCMASK 0x3FFFF   // 18 bits: NN=200000 < 262144

typedef _Float16 half_t;

// ======== CSR build, bucketed, packed ========
__global__ void hist_bkt(const int* __restrict__ dst, int* __restrict__ bcnt) {
    __shared__ int h[NBKT];
    for (int i = threadIdx.x; i < NBKT; i += 256) h[i] = 0;
    __syncthreads();
    int stride = gridDim.x * blockDim.x;
    for (int e = blockIdx.x * blockDim.x + threadIdx.x; e < NE; e += stride)
        atomicAdd(&h[dst[e] >> BSHIFT], 1);
    __syncthreads();
    for (int i = threadIdx.x; i < NBKT; i += 256)
        if (h[i]) atomicAdd(&bcnt[i], h[i]);
}

__global__ void scan_bkt(const int* __restrict__ bcnt, int* __restrict__ bbase,
                         int* __restrict__ bcur) {
    __shared__ int sh[256];
    int t = threadIdx.x;
    int v[4]; int own = 0;
    #pragma unroll
    for (int i = 0; i < 4; ++i) {
        int idx = t * 4 + i;
        v[i] = (idx < NBKT) ? bcnt[idx] : 0;
        own += v[i];
    }
    sh[t] = own; __syncthreads();
    for (int off = 1; off < 256; off <<= 1) {
        int x = (t >= off) ? sh[t - off] : 0;
        __syncthreads();
        sh[t] += x;
        __syncthreads();
    }
    int excl = sh[t] - own;
    #pragma unroll
    for (int i = 0; i < 4; ++i) {
        int idx = t * 4 + i;
        if (idx < NBKT) { bbase[idx] = excl; bcur[idx] = excl; excl += v[i]; }
    }
}

__global__ void partition_pairs(const int* __restrict__ src, const int* __restrict__ dst,
                                int* __restrict__ bcur, unsigned int* __restrict__ pairs) {
    __shared__ int h[NBKT];
    __shared__ int base[NBKT];
    int e0 = blockIdx.x * EPB;
    int e1 = min(e0 + EPB, NE);
    for (int i = threadIdx.x; i < NBKT; i += 256) h[i] = 0;
    __syncthreads();
    for (int e = e0 + threadIdx.x; e < e1; e += 256)
        atomicAdd(&h[dst[e] >> BSHIFT], 1);
    __syncthreads();
    for (int i = threadIdx.x; i < NBKT; i += 256) {
        int c = h[i];
        base[i] = c ? atomicAdd(&bcur[i], c) : 0;
        h[i] = 0;
    }
    __syncthreads();
    for (int e = e0 + threadIdx.x; e < e1; e += 256) {
        int d = dst[e];
        int bk = d >> BSHIFT;
        int off = atomicAdd(&h[bk], 1);
        pairs[base[bk] + off] =
            ((unsigned int)(d & ((1 << BSHIFT) - 1)) << 18) | (unsigned int)src[e];
    }
}

__global__ void bucket_deg(const unsigned int* __restrict__ pairs,
                           const int* __restrict__ bbase, const int* __restrict__ bcur,
                           int* __restrict__ deg, float* __restrict__ inv) {
    __shared__ int h[1 << BSHIFT];
    int bk = blockIdx.x;
    h[threadIdx.x] = 0;
    __syncthreads();
    int p0 = bbase[bk], p1 = bcur[bk];
    for (int i = p0 + threadIdx.x; i < p1; i += 256)
        atomicAdd(&h[pairs[i] >> 18], 1);
    __syncthreads();
    int n = (bk << BSHIFT) + threadIdx.x;
    if (n < NN) {
        int d = h[threadIdx.x];
        deg[n] = d;
        inv[n] = 1.0f / fmaxf((float)d, 1.0f);
    }
}

__global__ void chunk_sums(const int* __restrict__ deg, int* __restrict__ bsum) {
    __shared__ int red[256];
    int b = blockIdx.x, t = threadIdx.x;
    int base = b * 1024 + t;
    int s = 0;
    #pragma unroll
    for (int i = 0; i < 4; ++i) { int idx = base + i * 256; if (idx < NN) s += deg[idx]; }
    red[t] = s; __syncthreads();
    for (int off = 128; off > 0; off >>= 1) {
        if (t < off) red[t] += red[t + off];
        __syncthreads();
    }
    if (t == 0) bsum[b] = red[0];
}

__global__ void scan_bsums(int* __restrict__ bsum, int* __restrict__ row_ptr) {
    __shared__ int sh[256];
    int t = threadIdx.x;
    int own = (t < NB) ? bsum[t] : 0;
    sh[t] = own; __syncthreads();
    for (int off = 1; off < 256; off <<= 1) {
        int v = (t >= off) ? sh[t - off] : 0;
        __syncthreads();
        sh[t] += v;
        __syncthreads();
    }
    if (t < NB) bsum[t] = sh[t] - own;
    if (t == 0) row_ptr[NN] = NE;
}

__global__ void scan_write(const int* __restrict__ deg, const int* __restrict__ bsum,
                           int* __restrict__ row_ptr) {
    __shared__ int sh[256];
    int b = blockIdx.x, t = threadIdx.x;
    int base = b * 1024 + t * 4;
    int v0 = (base     < NN) ? deg[base]     : 0;
    int v1 = (base + 1 < NN) ? deg[base + 1] : 0;
    int v2 = (base + 2 < NN) ? deg[base + 2] : 0;
    int v3 = (base + 3 < NN) ? deg[base + 3] : 0;
    int own = v0 + v1 + v2 + v3;
    sh[t] = own; __syncthreads();
    for (int off = 1; off < 256; off <<= 1) {
        int x = (t >= off) ? sh[t - off] : 0;
        __syncthreads();
        sh[t] += x;
        __syncthreads();
    }
    int excl = sh[t] - own + bsum[b];
    if (base     < NN) { row_ptr[base]     = excl; excl += v0; }
    if (base + 1 < NN) { row_ptr[base + 1] = excl; excl += v1; }
    if (base + 2 < NN) { row_ptr[base + 2] = excl; excl += v2; }
    if (base + 3 < NN) { row_ptr[base + 3] = excl; }
}

__global__ void bucket_scatter(const unsigned int* __restrict__ pairs,
                               const int* __restrict__ bbase, const int* __restrict__ bcur,
                               const int* __restrict__ row_ptr, int* __restrict__ csr_src) {
    __shared__ int cur[1 << BSHIFT];
    int bk = blockIdx.x;
    int n0 = bk << BSHIFT;
    int nend = min(n0 + (1 << BSHIFT), NN);
    if (threadIdx.x < nend - n0) cur[threadIdx.x] = row_ptr[n0 + threadIdx.x];
    __syncthreads();
    int p0 = bbase[bk], p1 = bcur[bk];
    for (int i = p0 + threadIdx.x; i < p1; i += 256) {
        unsigned int pr = pairs[i];
        int pos = atomicAdd(&cur[pr >> 18], 1);
        csr_src[pos] = (int)(pr & SRCMASK);
    }
}

// ================= f32 -> fp16 conversion (8 elems/thread) =================
__global__ void f32_to_h8(const float* __restrict__ in, half_t* __restrict__ out, int total8) {
    int tid = blockIdx.x * blockDim.x + threadIdx.x;
    if (tid >= total8) return;
    const float4 a = ((const float4*)in)[tid * 2];
    const float4 b = ((const float4*)in)[tid * 2 + 1];
    union { uint4 u; half_t h[8]; } r;
    r.h[0] = (half_t)a.x; r.h[1] = (half_t)a.y; r.h[2] = (half_t)a.z; r.h[3] = (half_t)a.w;
    r.h[4] = (half_t)b.x; r.h[5] = (half_t)b.y; r.h[6] = (half_t)b.z; r.h[7] = (half_t)b.w;
    ((uint4*)out)[tid] = r.u;
}

// ================= fp16 pull-gather, LDS-staged edge indices =================
template<int DH, int Q, int MODE>
__global__ void gather_h(const int* __restrict__ rp, const int* __restrict__ cs,
                         const half_t* __restrict__ xn, const float* __restrict__ hs,
                         const float* __restrict__ bias, const float* __restrict__ inv,
                         float* __restrict__ out) {
    constexpr int NPB = 256 / Q;
    constexpr int CAP = 4096;
    __shared__ int shIdx[CAP];
    int n0 = blockIdx.x * NPB;
    if (n0 >= NN) return;
    int nEnd = min(n0 + NPB, NN);
    int e0 = rp[n0];
    int cnt = rp[nEnd] - e0;
    bool useLds = (cnt <= CAP);
    if (useLds)
        for (int i = threadIdx.x; i < cnt; i += 256) shIdx[i] = cs[e0 + i];
    __syncthreads();
    int t = threadIdx.x;
    int q = t % Q, l = t / Q;
    int n = n0 + l;
    if (l >= NPB || n >= NN) return;
    int s = rp[n] - e0, e = rp[n + 1] - e0;
    float acc[8] = {0.f, 0.f, 0.f, 0.f, 0.f, 0.f, 0.f, 0.f};
    union H8 { uint4 u; half_t h[8]; };
    if (useLds) {
        int j = s;
        for (; j + 2 <= e; j += 2) {
            H8 a, b;
            a.u = *(const uint4*)(xn + (size_t)shIdx[j]     * DH + q * 8);
            b.u = *(const uint4*)(xn + (size_t)shIdx[j + 1] * DH + q * 8);
            #pragma unroll
            for (int k = 0; k < 8; ++k) acc[k] += (float)a.h[k] + (float)b.h[k];
        }
        if (j < e) {
            H8 a; a.u = *(const uint4*)(xn + (size_t)shIdx[j] * DH + q * 8);
            #pragma unroll
            for (int k = 0; k < 8; ++k) acc[k] += (float)a.h[k];
        }
    } else {
        int j = s;
        for (; j + 2 <= e; j += 2) {
            H8 a, b;
            a.u = *(const uint4*)(xn + (size_t)cs[e0 + j]     * DH + q * 8);
            b.u = *(const uint4*)(xn + (size_t)cs[e0 + j + 1] * DH + q * 8);
            #pragma unroll
            for (int k = 0; k < 8; ++k) acc[k] += (float)a.h[k] + (float)b.h[k];
        }
        if (j < e) {
            H8 a; a.u = *(const uint4*)(xn + (size_t)cs[e0 + j] * DH + q * 8);
            #pragma unroll
            for (int k = 0; k < 8; ++k) acc[k] += (float)a.h[k];
        }
    }
    size_t base = (size_t)n * DH + q * 8;
    if (MODE == 0) {
        float4 r0 = make_float4(acc[0], acc[1], acc[2], acc[3]);
        float4 r1 = make_float4(acc[4], acc[5], acc[6], acc[7]);
        *(float4*)(out + base)     = r0;
        *(float4*)(out + base + 4) = r1;
    } else {
        float iv = inv[n];
        float4 h0 = *(const float4*)(hs + base);
        float4 b0 = *(const float4*)(bias + q * 8);
        float4 r0;
        r0.x = fmaxf(h0.x + iv * acc[0] + b0.x, 0.f);
        r0.y = fmaxf(h0.y + iv * acc[1] + b0.y, 0.f);
        r0.z = fmaxf(h0.z + iv * acc[2] + b0.z, 0.f);
        r0.w = fmaxf(h0.w + iv * acc[3] + b0.w, 0.f);
        *(float4*)(out + base) = r0;
        if (MODE == 1 || q < Q - 1) {
            float4 h1 = *(const float4*)(hs + base + 4);
            float4 b1 = *(const float4*)(bias + q * 8 + 4);
            float4 r1;
            r1.x = fmaxf(h1.x + iv * acc[4] + b1.x, 0.f);
            r1.y = fmaxf(h1.y + iv * acc[5] + b1.y, 0.f);
            r1.z = fmaxf(h1.z + iv * acc[6] + b1.z, 0.f);
            r1.w = fmaxf(h1.w + iv * acc[7] + b1.w, 0.f);
            *(float4*)(out + base + 4) = r1;
        }
    }
}

// scalar D=5 gather (f32), fused combine no relu
__global__ void gather_lds_s5(const int* __restrict__ rp, const int* __restrict__ cs,
                              const float* __restrict__ xn, const float* __restrict__ hs,
                              const float* __restrict__ bias, const float* __restrict__ inv,
                              float* __restrict__ out) {
    constexpr int D = 5, Q = 5, NPB = 51, CAP = 4096;
    __shared__ int shIdx[CAP];
    int n0 = blockIdx.x * NPB;
    if (n0 >= NN) return;
    int nEnd = min(n0 + NPB, NN);
    int e0 = rp[n0];
    int cnt = rp[nEnd] - e0;
    bool useLds = (cnt <= CAP);
    if (useLds)
        for (int i = threadIdx.x; i < cnt; i += 256) shIdx[i] = cs[e0 + i];
    __syncthreads();
    int t = threadIdx.x;
    int q = t % Q, l = t / Q;
    int n = n0 + l;
    if (l >= NPB || n >= NN) return;
    int s = rp[n] - e0, e = rp[n + 1] - e0;
    float acc = 0.f;
    if (useLds) {
        int j = s;
        for (; j + 2 <= e; j += 2)
            acc += xn[(size_t)shIdx[j] * D + q] + xn[(size_t)shIdx[j + 1] * D + q];
        if (j < e) acc += xn[(size_t)shIdx[j] * D + q];
    } else {
        int j = s;
        for (; j + 2 <= e; j += 2)
            acc += xn[(size_t)cs[e0 + j] * D + q] + xn[(size_t)cs[e0 + j + 1] * D + q];
        if (j < e) acc += xn[(size_t)cs[e0 + j] * D + q];
    }
    size_t oidx = (size_t)n * D + q;
    out[oidx] = hs[oidx] + inv[n] * acc + bias[q];
}

// ====== LDS-staged dual GEMM: hs f32 + hn fp16 ======
template<int DIN, int DINS, int DOUT, int DOUTS, int NPER>
__global__ void proj_dual_lds_h(const float* __restrict__ h,
                                const float* __restrict__ Ws, const float* __restrict__ Wn,
                                float* __restrict__ hs, half_t* __restrict__ hn) {
    constexpr int Q = DOUT / 4;
    constexpr int GROUPS = 256 / Q;
    constexpr int NPB = GROUPS * NPER;
    __shared__ float4 shW[DIN * 2 * Q];
    const float4* Ws4 = (const float4*)Ws;
    const float4* Wn4 = (const float4*)Wn;
    for (int i = threadIdx.x; i < DIN * Q; i += 256) {
        int k = i / Q, q = i - k * Q;
        shW[k * 2 * Q + q]     = Ws4[i];
        shW[k * 2 * Q + Q + q] = Wn4[i];
    }
    __syncthreads();
    int t = threadIdx.x;
    int q = t % Q, g = t / Q;
    if (g >= GROUPS) return;
    int n0 = blockIdx.x * NPB + g * NPER;
    if (n0 >= NN) return;
    union H4 { unsigned long long u; half_t hh[4]; };

    auto emit = [&](int n, const float4& aS, const float4& aN) {
        *(float4*)(hs + (size_t)n * DOUTS + q * 4) = aS;
        H4 r;
        r.hh[0] = (half_t)aN.x; r.hh[1] = (half_t)aN.y;
        r.hh[2] = (half_t)aN.z; r.hh[3] = (half_t)aN.w;
        *(unsigned long long*)(hn + (size_t)n * DOUTS + q * 4) = r.u;
        if (DOUTS > DOUT && q == Q - 1) {
            H4 z; z.u = 0ull;
            *(unsigned long long*)(hn + (size_t)n * DOUTS + DOUT) = z.u;
        }
    };

    if (n0 + NPER <= NN) {
        float4 aS[NPER], aN[NPER];
        #pragma unroll
        for (int i = 0; i < NPER; ++i) {
            aS[i] = make_float4(0.f, 0.f, 0.f, 0.f);
            aN[i] = make_float4(0.f, 0.f, 0.f, 0.f);
        }
        const float* hp = h + (size_t)n0 * DINS;
        for (int kk = 0; kk < DIN; kk += 4) {
            float4 hv[NPER];
            #pragma unroll
            for (int i = 0; i < NPER; ++i)
                hv[i] = *(const float4*)(hp + (size_t)i * DINS + kk);
            #pragma unroll
            for (int dk = 0; dk < 4; ++dk) {
                float4 ws = shW[(kk + dk) * 2 * Q + q];
                float4 wn = shW[(kk + dk) * 2 * Q + Q + q];
                #pragma unroll
                for (int i = 0; i < NPER; ++i) {
                    float v = ((const float*)&hv[i])[dk];
                    aS[i].x = fmaf(v, ws.x, aS[i].x); aS[i].y = fmaf(v, ws.y, aS[i].y);
                    aS[i].z = fmaf(v, ws.z, aS[i].z); aS[i].w = fmaf(v, ws.w, aS[i].w);
                    aN[i].x = fmaf(v, wn.x, aN[i].x); aN[i].y = fmaf(v, wn.y, aN[i].y);
                    aN[i].z = fmaf(v, wn.z, aN[i].z); aN[i].w = fmaf(v, wn.w, aN[i].w);
                }
            }
        }
        #pragma unroll
        for (int i = 0; i < NPER; ++i) emit(n0 + i, aS[i], aN[i]);
    } else {
        for (int i = 0; i < NPER; ++i) {
            int n = n0 + i;
            if (n >= NN) break;
            float4 aS = make_float4(0.f, 0.f, 0.f, 0.f);
            float4 aN = make_float4(0.f, 0.f, 0.f, 0.f);
            const float* hp = h + (size_t)n * DINS;
            for (int kk = 0; kk < DIN; kk += 4) {
                float4 hv = *(const float4*)(hp + kk);
                #pragma unroll
                for (int dk = 0; dk < 4; ++dk) {
                    float4 ws = shW[(kk + dk) * 2 * Q + q];
                    float4 wn = shW[(kk + dk) * 2 * Q + Q + q];
                    float v = ((const float*)&hv)[dk];
                    aS.x = fmaf(v, ws.x, aS.x); aS.y = fmaf(v, ws.y, aS.y);
                    aS.z = fmaf(v, ws.z, aS.z); aS.w = fmaf(v, ws.w, aS.w);
                    aN.x = fmaf(v, wn.x, aN.x); aN.y = fmaf(v, wn.y, aN.y);
                    aN.z = fmaf(v, wn.z, aN.z); aN.w = fmaf(v, wn.w, aN.w);
                }
            }
            emit(n, aS, aN);
        }
    }
}

// scalar dual projection, f32 outputs (DOUT=5); DINS = input row stride
template<int DINS, int DIN, int DOUT>
__global__ void proj_dual_s(const float* __restrict__ h,
                            const float* __restrict__ Ws, const float* __restrict__ Wn,
                            float* __restrict__ hs, float* __restrict__ hn) {
    const int total = NN * DOUT;
    int tid = blockIdx.x * blockDim.x + threadIdx.x;
    if (tid >= total) return;
    int n = tid / DOUT, j = tid - n * DOUT;
    const float* r = h + (size_t)n * DINS;
    float aS = 0.f, aN = 0.f;
    #pragma unroll 4
    for (int k = 0; k < DIN; ++k) {
        float v = r[k];
        aS = fmaf(v, Ws[k * DOUT + j], aS);
        aN = fmaf(v, Wn[k * DOUT + j], aN);
    }
    hs[tid] = aS;
    hn[tid] = aN;
}

// ================= layer 0 with LDS-staged weights =================
__global__ void layer0_lds(const float* __restrict__ feat, const float* __restrict__ agg,
                           const float* __restrict__ Ws, const float* __restrict__ Wn,
                           const float* __restrict__ bias, const float* __restrict__ inv,
                           float* __restrict__ out) {
    constexpr int DIN = 32, DOUT = 128, Q = 32, NPER = 4;
    constexpr int NPB = 8 * NPER;
    __shared__ float4 shW[DIN * 2 * Q];
    const float4* Ws4 = (const float4*)Ws;
    const float4* Wn4 = (const float4*)Wn;
    for (int i = threadIdx.x; i < DIN * Q; i += 256) {
        int k = i / Q, q = i - k * Q;
        shW[k * 2 * Q + q]     = Ws4[i];
        shW[k * 2 * Q + Q + q] = Wn4[i];
    }
    __syncthreads();
    int t = threadIdx.x;
    int q = t & 31, g = t >> 5;
    int n0 = blockIdx.x * NPB + g * NPER;
    if (n0 >= NN) return;
    float4 bb = *(const float4*)(bias + q * 4);

    if (n0 + NPER <= NN) {
        float4 aS[NPER], aN[NPER];
        #pragma unroll
        for (int i = 0; i < NPER; ++i) {
            aS[i] = make_float4(0.f, 0.f, 0.f, 0.f);
            aN[i] = make_float4(0.f, 0.f, 0.f, 0.f);
        }
        const float* fp = feat + (size_t)n0 * DIN;
        const float* ap = agg + (size_t)n0 * DIN;
        for (int kk = 0; kk < DIN; kk += 4) {
            float4 fv[NPER], av[NPER];
            #pragma unroll
            for (int i = 0; i < NPER; ++i) {
                fv[i] = *(const float4*)(fp + (size_t)i * DIN + kk);
                av[i] = *(const float4*)(ap + (size_t)i * DIN + kk);
            }
            #pragma unroll
            for (int dk = 0; dk < 4; ++dk) {
                float4 ws = shW[(kk + dk) * 2 * Q + q];
                float4 wn = shW[(kk + dk) * 2 * Q + Q + q];
                #pragma unroll
                for (int i = 0; i < NPER; ++i) {
                    float f = ((const float*)&fv[i])[dk];
                    float a = ((const float*)&av[i])[dk];
                    aS[i].x = fmaf(f, ws.x, aS[i].x); aS[i].y = fmaf(f, ws.y, aS[i].y);
                    aS[i].z = fmaf(f, ws.z, aS[i].z); aS[i].w = fmaf(f, ws.w, aS[i].w);
                    aN[i].x = fmaf(a, wn.x, aN[i].x); aN[i].y = fmaf(a, wn.y, aN[i].y);
                    aN[i].z = fmaf(a, wn.z, aN[i].z); aN[i].w = fmaf(a, wn.w, aN[i].w);
                }
            }
        }
        #pragma unroll
        for (int i = 0; i < NPER; ++i) {
            float iv = inv[n0 + i];
            float4 r;
            r.x = fmaxf(aS[i].x + iv * aN[i].x + bb.x, 0.f);
            r.y = fmaxf(aS[i].y + iv * aN[i].y + bb.y, 0.f);
            r.z = fmaxf(aS[i].z + iv * aN[i].z + bb.z, 0.f);
            r.w = fmaxf(aS[i].w + iv * aN[i].w + bb.w, 0.f);
            *(float4*)(out + (size_t)(n0 + i) * DOUT + q * 4) = r;
        }
    } else {
        for (int i = 0; i < NPER; ++i) {
            int n = n0 + i;
            if (n >= NN) break;
            float4 aS = make_float4(0.f, 0.f, 0.f, 0.f);
            float4 aN = make_float4(0.f, 0.f, 0.f, 0.f);
            for (int kk = 0; kk < DIN; kk += 4) {
                float4 fv = *(const float4*)(feat + (size_t)n * DIN + kk);
                float4 av = *(const float4*)(agg + (size_t)n * DIN + kk);
                #pragma unroll
                for (int dk = 0; dk < 4; ++dk) {
                    float4 ws = shW[(kk + dk) * 2 * Q + q];
                    float4 wn = shW[(kk + dk) * 2 * Q + Q + q];
                    float f = ((const float*)&fv)[dk];
                    float a = ((const float*)&av)[dk];
                    aS.x = fmaf(f, ws.x, aS.x); aS.y = fmaf(f, ws.y, aS.y);
                    aS.z = fmaf(f, ws.z, aS.z); aS.w = fmaf(f, ws.w, aS.w);
                    aN.x = fmaf(a, wn.x, aN.x); aN.y = fmaf(a, wn.y, aN.y);
                    aN.z = fmaf(a, wn.z, aN.z); aN.w = fmaf(a, wn.w, aN.w);
                }
            }
            float iv = inv[n];
            float4 r;
            r.x = fmaxf(aS.x + iv * aN.x + bb.x, 0.f);
            r.y = fmaxf(aS.y + iv * aN.y + bb.y, 0.f);
            r.z = fmaxf(aS.z + iv * aN.z + bb.z, 0.f);
            r.w = fmaxf(aS.w + iv * aN.w + bb.w, 0.f);
            *(float4*)(out + (size_t)n * DOUT + q * 4) = r;
        }
    }
}

// ---------------- per-graph mean readout ----------------
__global__ void readout_graph(const float* __restrict__ h, const int* __restrict__ gid,
                              float* __restrict__ out) {
    const int g = blockIdx.x;
    const int t = threadIdx.x;
    int lo = 0, hi = NN;
    while (lo < hi) { int mid = (lo + hi) >> 1; if (gid[mid] < g) lo = mid + 1; else hi = mid; }
    const int start = lo;
    hi = NN;
    while (lo < hi) { int mid = (lo + hi) >> 1; if (gid[mid] <= g) lo = mid + 1; else hi = mid; }
    const int end = lo;

    float acc[5] = {0.f, 0.f, 0.f, 0.f, 0.f};
    for (int n = start + t; n < end; n += blockDim.x) {
        const float* row = h + (size_t)n * 5;
        #pragma unroll
        for (int j = 0; j < 5; ++j) acc[j] += row[j];
    }
    __shared__ float sh[5][256];
    #pragma unroll
    for (int j = 0; j < 5; ++j) sh[j][t] = acc[j];
    __syncthreads();
    for (int off = 128; off > 0; off >>= 1) {
        if (t < off) {
            #pragma unroll
            for (int j = 0; j < 5; ++j) sh[j][t] += sh[j][t + off];
        }
        __syncthreads();
    }
    if (t < 5) {
        float cnt = (float)(end - start);
        out[g * 5 + t] = sh[t][0] / fmaxf(cnt, 1.f);
    }
}

extern "C" void kernel_launch(void* const* d_in, const int* in_sizes, int n_in,
                              void* d_out, int out_size, void* d_ws, size_t ws_size,
                              hipStream_t stream) {
    const float* feat = (const float*)d_in[0];
    const int*   src  = (const int*)d_in[1];
    const int*   dst  = (const int*)d_in[2];
    const int*   gid  = (const int*)d_in[3];
    const float* Ws0 = (const float*)d_in[4],  *Wn0 = (const float*)d_in[5],  *b0 = (const float*)d_in[6];
    const float* Ws1 = (const float*)d_in[7],  *Wn1 = (const float*)d_in[8],  *b1 = (const float*)d_in[9];
    const float* Ws2 = (const float*)d_in[10], *Wn2 = (const float*)d_in[11], *b2 = (const float*)d_in[12];
    const float* Ws3 = (const float*)d_in[13], *Wn3 = (const float*)d_in[14], *b3 = (const float*)d_in[15];
    float* out = (float*)d_out;

    // ---- workspace layout ----
    float* ws   = (float*)d_ws;
    float* inv  = ws;                            // NN
    float* bufA = inv  + NN;                     // NN*128 f32 (h between layers)
    float* bufB = bufA + (size_t)NN * 128;       // NN*48 f32 (agg32 / hs) — pairs live here during build
    float* bufC = bufB + (size_t)NN * 48;        // NN*48 f32 region: fp16 tables / hn5 f32
    int*   deg     = (int*)(bufC + (size_t)NN * 48); // NN
    int*   row_ptr = deg + NN;                   // NN+1
    int*   bsum    = row_ptr + NN + 1;           // 256
    int*   bcnt    = bsum + 256;                 // NBKT
    int*   bbase   = bcnt + NBKT;                // NBKT
    int*   bcur    = bbase + NBKT;               // NBKT
    int*   csr_src = bcur + NBKT;                // NE
    unsigned int* pairs = (unsigned int*)bufB;   // NE packed (12.8 MB), dead after build
    half_t* hbuf  = (half_t*)bufC;               // fp16 gather tables (<= NN*48 halves)
    float*  hn5   = bufC;                        // f32 NN*5 for layer 3 (hbuf dead by then)

    const dim3 blk(256);

    // ---- CSR build: bucketed counting sort, packed ----
    hipMemsetAsync(bcnt, 0, NBKT * sizeof(int), stream);
    hist_bkt<<<2048, blk, 0, stream>>>(dst, bcnt);
    scan_bkt<<<1, blk, 0, stream>>>(bcnt, bbase, bcur);
    partition_pairs<<<(NE + EPB - 1) / EPB, blk, 0, stream>>>(src, dst, bcur, pairs);
    bucket_deg<<<NBKT, blk, 0, stream>>>(pairs, bbase, bcur, deg, inv);
    chunk_sums<<<NB, blk, 0, stream>>>(deg, bsum);
    scan_bsums<<<1, blk, 0, stream>>>(bsum, row_ptr);
    scan_write<<<NB, blk, 0, stream>>>(deg, bsum, row_ptr);
    bucket_scatter<<<NBKT, blk, 0, stream>>>(pairs, bbase, bcur, row_ptr, csr_src);

    // ---- layer 0: feat->fp16, pull-aggregate 32 (64B rows), LDS-GEMM to 128 ----
    f32_to_h8<<<(NN * 4 + 255) / 256, blk, 0, stream>>>(feat, hbuf, NN * 4);
    gather_h<32, 4, 0><<<(NN + 63) / 64, blk, 0, stream>>>(
        row_ptr, csr_src, hbuf, nullptr, nullptr, nullptr, bufB);
    layer0_lds<<<(NN + 31) / 32, blk, 0, stream>>>(feat, bufB, Ws0, Wn0, b0, inv, bufA);

    // ---- layer 1: LDS-GEMM 128->48 (hs f32 + hn fp16), gather 48h (96B rows), combine ----
    proj_dual_lds_h<128, 128, 48, 48, 4><<<(NN + 83) / 84, blk, 0, stream>>>(
        bufA, Ws1, Wn1, bufB, hbuf);
    gather_h<48, 6, 1><<<(NN + 41) / 42, blk, 0, stream>>>(
        row_ptr, csr_src, hbuf, bufB, b1, inv, bufA);

    // ---- layer 2: LDS-GEMM 48->28 (padded to 32h = 64B rows), gather, combine ----
    proj_dual_lds_h<48, 48, 28, 32, 4><<<(NN + 143) / 144, blk, 0, stream>>>(
        bufA, Ws2, Wn2, bufB, hbuf);
    gather_h<32, 4, 2><<<(NN + 63) / 64, blk, 0, stream>>>(
        row_ptr, csr_src, hbuf, bufB, b2, inv, bufA);   // h2: stride 32, 28 real dims

    // ---- layer 3: 28->5 (dual f32, input stride 32), gather 5, combine (no relu) ----
    proj_dual_s<32, 28, 5><<<(NN * 5 + 255) / 256, blk, 0, stream>>>(bufA, Ws3, Wn3, bufB, hn5);
    gather_lds_s5<<<(NN + 50) / 51, blk, 0, stream>>>(row_ptr, csr_src, hn5, bufB, b3, inv, bufA);

    // ---- per-graph mean readout ----
    readout_graph<<<NG, blk, 0, stream>>>(bufA, gid, out);
}